// Round 1
// baseline (673.168 us; speedup 1.0000x reference)
//
#include <hip/hip_runtime.h>
#include <math.h>

#define BB 16
#define NN 4096
#define DD 128
#define KK 256          // C*P = 4*64
#define NROWS (BB*NN)   // 65536
#define WIN 7
#define HWIN 3
#define ALPHA 0.5f
#define EPS 1e-5f

// ---------------------------------------------------------------------------
// Kernel A: h[src] = X[src] @ W^T + b  (f32), plus per-feature sum / sumsq
// grid: 4096 blocks (2048 per source), 256 threads, 32 rows x 128 cols / block
// ---------------------------------------------------------------------------
__global__ __launch_bounds__(256) void k_embed_gemm(
    const float* __restrict__ x,
    const float* __restrict__ xt,
    const float* __restrict__ W,     // [D][K] row-major
    const float* __restrict__ bvec,  // [D]
    float* __restrict__ h_out,       // [2][NROWS][D]
    float* __restrict__ sums)        // [2][2][D]: sum then sumsq
{
    const int blk  = blockIdx.x;
    const int src  = blk >> 11;          // 2048 blocks per source
    const int tile = blk & 2047;
    const int row0 = tile * 32;
    const float* __restrict__ X = src ? xt : x;
    float* __restrict__ H = h_out + (size_t)src * NROWS * DD;

    __shared__ float Xs[32 * KK];        // 32 KiB

    const int t = threadIdx.x;

    // stage 32 rows of X (contiguous 32 KiB) into LDS, coalesced float4
    {
        const float4* __restrict__ Xg = (const float4*)(X + (size_t)row0 * KK);
        float4* Xs4 = (float4*)Xs;
        #pragma unroll
        for (int p = 0; p < 8; ++p)
            Xs4[t + p * 256] = Xg[t + p * 256];
    }
    __syncthreads();

    const int dg = t & 31;               // d-group: d0 = dg*4
    const int rg = t >> 5;               // row-group: rows rg*4 .. rg*4+3
    const int d0 = dg * 4;

    float acc[4][4];
    #pragma unroll
    for (int i = 0; i < 4; ++i)
        #pragma unroll
        for (int j = 0; j < 4; ++j) acc[i][j] = 0.f;

    const float4* __restrict__ W4 = (const float4*)W;   // [D][64] float4
    const float4* Xs4 = (const float4*)Xs;              // [32][64] float4

    #pragma unroll 4
    for (int k4 = 0; k4 < 64; ++k4) {
        const float4 w0 = W4[(d0 + 0) * 64 + k4];
        const float4 w1 = W4[(d0 + 1) * 64 + k4];
        const float4 w2 = W4[(d0 + 2) * 64 + k4];
        const float4 w3 = W4[(d0 + 3) * 64 + k4];
        #pragma unroll
        for (int i = 0; i < 4; ++i) {
            const float4 xv = Xs4[(rg * 4 + i) * 64 + k4];   // wave-broadcast read
            acc[i][0] += xv.x * w0.x + xv.y * w0.y + xv.z * w0.z + xv.w * w0.w;
            acc[i][1] += xv.x * w1.x + xv.y * w1.y + xv.z * w1.z + xv.w * w1.w;
            acc[i][2] += xv.x * w2.x + xv.y * w2.y + xv.z * w2.z + xv.w * w2.w;
            acc[i][3] += xv.x * w3.x + xv.y * w3.y + xv.z * w3.z + xv.w * w3.w;
        }
    }

    // add bias (stats are over h INCLUDING bias)
    const float b0 = bvec[d0 + 0], b1 = bvec[d0 + 1];
    const float b2 = bvec[d0 + 2], b3 = bvec[d0 + 3];
    #pragma unroll
    for (int i = 0; i < 4; ++i) {
        acc[i][0] += b0; acc[i][1] += b1; acc[i][2] += b2; acc[i][3] += b3;
    }

    // store raw h (normalization happens later with global stats)
    #pragma unroll
    for (int i = 0; i < 4; ++i) {
        float4 hv = make_float4(acc[i][0], acc[i][1], acc[i][2], acc[i][3]);
        *(float4*)(&H[(size_t)(row0 + rg * 4 + i) * DD + d0]) = hv;
    }

    // block-level reduction of sum / sumsq, then one atomic per feature
    __syncthreads();                     // done with staged X, reuse LDS
    float s[4], q[4];
    #pragma unroll
    for (int j = 0; j < 4; ++j) {
        s[j] = acc[0][j] + acc[1][j] + acc[2][j] + acc[3][j];
        q[j] = acc[0][j] * acc[0][j] + acc[1][j] * acc[1][j] +
               acc[2][j] * acc[2][j] + acc[3][j] * acc[3][j];
    }
    float* red = Xs;                     // [0..1023] sum, [1024..2047] sumsq
    #pragma unroll
    for (int j = 0; j < 4; ++j) {
        red[rg * 128 + d0 + j]        = s[j];
        red[1024 + rg * 128 + d0 + j] = q[j];
    }
    __syncthreads();
    if (t < 128) {
        float S = 0.f, Q = 0.f;
        #pragma unroll
        for (int r = 0; r < 8; ++r) {
            S += red[r * 128 + t];
            Q += red[1024 + r * 128 + t];
        }
        atomicAdd(&sums[src * 256 + t], S);
        atomicAdd(&sums[src * 256 + 128 + t], Q);
    }
}

// ---------------------------------------------------------------------------
// Kernel B: finalize stats -> scale/shift per source
// ---------------------------------------------------------------------------
__global__ void k_stats(const float* __restrict__ sums,
                        const float* __restrict__ gamma,
                        const float* __restrict__ beta,
                        float* __restrict__ ss)   // [2][2][D]: scale, shift
{
    const int t = threadIdx.x;
    if (t < 256) {
        const int src = t >> 7;
        const int d   = t & 127;
        const float invn = 1.0f / (float)NROWS;
        const float mean = sums[src * 256 + d] * invn;
        const float var  = sums[src * 256 + 128 + d] * invn - mean * mean;
        const float sc   = gamma[d] / sqrtf(var + EPS);
        const float sh   = beta[d] - mean * sc;
        ss[src * 256 + d]       = sc;
        ss[src * 256 + 128 + d] = sh;
    }
}

// ---------------------------------------------------------------------------
// Kernel C: normalize + leaky, windowed sim, masked softmax, weighted blend
// grid: 16*128 = 2048 blocks (32 n-positions each), 256 threads
// ---------------------------------------------------------------------------
__device__ __forceinline__ float lrelu(float v) { return v >= 0.f ? v : 0.1f * v; }

__global__ __launch_bounds__(256) void k_attn(
    const float* __restrict__ x,
    const float* __restrict__ xt,
    const float* __restrict__ h,    // [2][NROWS][D]
    const float* __restrict__ ss,   // [2][2][D]
    float* __restrict__ out,        // [B*N*K]
    float* __restrict__ feat)       // [B*N*7]
{
    const int blk  = blockIdx.x;
    const int bb   = blk >> 7;       // batch
    const int tile = blk & 127;
    const int n0   = tile * 32;
    const int t    = threadIdx.x;

    __shared__ float ex[32][132];
    __shared__ float et[38][132];
    __shared__ float attn[32][8];

    const float* __restrict__ Hx = h;
    const float* __restrict__ Ht = h + (size_t)NROWS * DD;
    const size_t rowbase = (size_t)bb * NN;

    // emb_x: 32 rows, normalize + leaky on the fly
    #pragma unroll
    for (int p = 0; p < 4; ++p) {
        const int idx = t + p * 256;           // 1024 float4
        const int r = idx >> 5, c4 = idx & 31;
        const float4 hv = *(const float4*)(&Hx[(rowbase + n0 + r) * DD + c4 * 4]);
        const float4 sc = *(const float4*)(&ss[c4 * 4]);
        const float4 sh = *(const float4*)(&ss[128 + c4 * 4]);
        ex[r][c4 * 4 + 0] = lrelu(hv.x * sc.x + sh.x);
        ex[r][c4 * 4 + 1] = lrelu(hv.y * sc.y + sh.y);
        ex[r][c4 * 4 + 2] = lrelu(hv.z * sc.z + sh.z);
        ex[r][c4 * 4 + 3] = lrelu(hv.w * sc.w + sh.w);
    }
    // emb_t: 38 rows (clamped window), normalize + leaky
    #pragma unroll
    for (int p = 0; p < 5; ++p) {
        const int idx = t + p * 256;           // 1216 float4
        if (idx < 1216) {
            const int r = idx >> 5, c4 = idx & 31;
            int g = n0 - HWIN + r;
            g = min(max(g, 0), NN - 1);
            const float4 hv = *(const float4*)(&Ht[(rowbase + g) * DD + c4 * 4]);
            const float4 sc = *(const float4*)(&ss[256 + c4 * 4]);
            const float4 sh = *(const float4*)(&ss[384 + c4 * 4]);
            et[r][c4 * 4 + 0] = lrelu(hv.x * sc.x + sh.x);
            et[r][c4 * 4 + 1] = lrelu(hv.y * sc.y + sh.y);
            et[r][c4 * 4 + 2] = lrelu(hv.z * sc.z + sh.z);
            et[r][c4 * 4 + 3] = lrelu(hv.w * sc.w + sh.w);
        }
    }
    __syncthreads();

    // sim: 32 n x 7 w = 224 dots of length 128
    if (t < 224) {
        const int n_i = t / 7;
        const int w   = t % 7;
        const float* a = &ex[n_i][0];
        const float* b = &et[n_i + w][0];
        float acc = 0.f;
        #pragma unroll
        for (int d4 = 0; d4 < 128; d4 += 4) {
            const float4 av = *(const float4*)(a + d4);
            const float4 bv = *(const float4*)(b + d4);
            acc += av.x * bv.x + av.y * bv.y + av.z * bv.z + av.w * bv.w;
        }
        feat[(rowbase + n0 + n_i) * WIN + w] = acc;   // feat_fused = raw sim
        attn[n_i][w] = acc;                           // stash sim
    }
    __syncthreads();

    // masked softmax over the window, per n
    if (t < 32) {
        const int n = n0 + t;
        float mx = -1e30f;
        #pragma unroll
        for (int w = 0; w < WIN; ++w) {
            const int c = n + w - HWIN;
            if (c >= 0 && c < NN) mx = fmaxf(mx, attn[t][w]);
        }
        float e[WIN];
        float esum = 0.f;
        #pragma unroll
        for (int w = 0; w < WIN; ++w) {
            const int c = n + w - HWIN;
            const bool valid = (c >= 0 && c < NN);
            e[w] = valid ? expf(attn[t][w] - mx) : 0.f;
            esum += e[w];
        }
        const float inv = 1.0f / esum;
        #pragma unroll
        for (int w = 0; w < WIN; ++w) attn[t][w] = e[w] * inv;
    }
    __syncthreads();

    // out = alpha*x + (1-alpha) * sum_w attn[w] * xt[clamped window row]
    #pragma unroll
    for (int p = 0; p < 8; ++p) {
        const int idx = t + p * 256;            // 2048 float4 = 32 rows x 64
        const int n_i = idx >> 6, e4 = idx & 63;
        const int n = n0 + n_i;
        const float4 xv = *(const float4*)(&x[(rowbase + n) * KK + e4 * 4]);
        float4 acc = make_float4(0.f, 0.f, 0.f, 0.f);
        #pragma unroll
        for (int w = 0; w < WIN; ++w) {
            int g = n + w - HWIN;
            g = min(max(g, 0), NN - 1);
            const float aw = attn[n_i][w];
            const float4 tv = *(const float4*)(&xt[(rowbase + g) * KK + e4 * 4]);
            acc.x += aw * tv.x;
            acc.y += aw * tv.y;
            acc.z += aw * tv.z;
            acc.w += aw * tv.w;
        }
        float4 o;
        o.x = ALPHA * xv.x + (1.f - ALPHA) * acc.x;
        o.y = ALPHA * xv.y + (1.f - ALPHA) * acc.y;
        o.z = ALPHA * xv.z + (1.f - ALPHA) * acc.z;
        o.w = ALPHA * xv.w + (1.f - ALPHA) * acc.w;
        *(float4*)(&out[(rowbase + n) * KK + e4 * 4]) = o;
    }
}

// ---------------------------------------------------------------------------
extern "C" void kernel_launch(void* const* d_in, const int* in_sizes, int n_in,
                              void* d_out, int out_size, void* d_ws, size_t ws_size,
                              hipStream_t stream) {
    const float* x     = (const float*)d_in[0];
    const float* xt    = (const float*)d_in[1];
    const float* W     = (const float*)d_in[2];
    const float* bvec  = (const float*)d_in[3];
    const float* gamma = (const float*)d_in[4];
    const float* beta  = (const float*)d_in[5];

    float* out  = (float*)d_out;
    float* feat = out + (size_t)BB * NN * KK;   // 16,777,216 floats of `out` first

    char*  ws   = (char*)d_ws;
    float* h    = (float*)ws;                               // 2 x 65536 x 128 f32 = 64 MiB
    float* sums = (float*)(ws + (size_t)67108864);          // 512 f32
    float* ss   = (float*)(ws + (size_t)67110912);          // 512 f32

    hipMemsetAsync(sums, 0, 512 * sizeof(float), stream);
    k_embed_gemm<<<4096, 256, 0, stream>>>(x, xt, W, bvec, h, sums);
    k_stats<<<1, 256, 0, stream>>>(sums, gamma, beta, ss);
    k_attn<<<2048, 256, 0, stream>>>(x, xt, h, ss, out, feat);
}

// Round 2
// 237.486 us; speedup vs baseline: 2.8346x; 2.8346x over previous
//
#include <hip/hip_runtime.h>
#include <math.h>

#define BB 16
#define NN 4096
#define DD 128
#define KK 256          // C*P = 4*64
#define NROWS (BB*NN)   // 65536
#define WIN 7
#define HWIN 3
#define ALPHA 0.5f
#define EPS 1e-5f

typedef __attribute__((ext_vector_type(8))) short bf16x8;
typedef __attribute__((ext_vector_type(4))) float f32x4;

__device__ __forceinline__ unsigned short f2b(float f) {     // f32 -> bf16 RNE
    unsigned u = __float_as_uint(f);
    u += 0x7FFFu + ((u >> 16) & 1u);
    return (unsigned short)(u >> 16);
}
__device__ __forceinline__ float b2f(unsigned short s) {
    return __uint_as_float(((unsigned)s) << 16);
}
__device__ __forceinline__ float b2f_lo(unsigned v) { return __uint_as_float(v << 16); }
__device__ __forceinline__ float b2f_hi(unsigned v) { return __uint_as_float(v & 0xFFFF0000u); }
__device__ __forceinline__ float lrelu(float v) { return v >= 0.f ? v : 0.1f * v; }

// ---------------------------------------------------------------------------
// Kernel A: h[src] = bf16mfma( X[src] @ W^T ) + b, h stored bf16,
//           plus per-feature sum / sumsq via f32 accumulators.
// grid: 2048 blocks (1024 per source), 256 threads, 64 rows x 128 cols / block
// ---------------------------------------------------------------------------
__global__ __launch_bounds__(256) void k_embed_mfma(
    const float* __restrict__ x,
    const float* __restrict__ xt,
    const float* __restrict__ W,      // [D][K] f32 row-major
    const float* __restrict__ bvec,   // [D]
    unsigned short* __restrict__ h_out, // [2][NROWS][D] bf16
    float* __restrict__ sums)         // [2][2][D]: sum then sumsq
{
    __shared__ unsigned short Wsh[128 * 128];  // 32 KB bf16, K-half, swizzled
    __shared__ unsigned short Xsh[64 * 128];   // 16 KB bf16, K-half, swizzled

    const int blk  = blockIdx.x;
    const int src  = blk >> 10;
    const int tile = blk & 1023;
    const int row0 = tile * 64;
    const float* __restrict__ X = src ? xt : x;
    unsigned short* __restrict__ H = h_out + (size_t)src * NROWS * DD;

    const int t    = threadIdx.x;
    const int lane = t & 63;
    const int w    = t >> 6;
    const int wm   = w >> 1;     // 0..1 : rows 32*wm .. +32
    const int wn   = w & 1;      // 0..1 : cols 64*wn .. +64

    f32x4 acc[2][4];
    #pragma unroll
    for (int m = 0; m < 2; ++m)
        #pragma unroll
        for (int n = 0; n < 4; ++n)
            #pragma unroll
            for (int j = 0; j < 4; ++j) acc[m][n][j] = 0.f;

    #pragma unroll
    for (int ph = 0; ph < 2; ++ph) {
        // ---- stage W K-half: 128 rows x 128 k, f32 -> bf16, swizzled LDS
        #pragma unroll
        for (int p = 0; p < 8; ++p) {
            const int j  = t + p * 256;          // 2048 chunks of 8
            const int r  = j >> 4, k8 = j & 15;
            const float* gp = &W[(size_t)r * KK + ph * 128 + k8 * 8];
            const float4 a = *(const float4*)(gp);
            const float4 bq = *(const float4*)(gp + 4);
            uint4 v;
            v.x = (unsigned)f2b(a.x)  | ((unsigned)f2b(a.y)  << 16);
            v.y = (unsigned)f2b(a.z)  | ((unsigned)f2b(a.w)  << 16);
            v.z = (unsigned)f2b(bq.x) | ((unsigned)f2b(bq.y) << 16);
            v.w = (unsigned)f2b(bq.z) | ((unsigned)f2b(bq.w) << 16);
            const int off = r * 256 + ((k8 * 16) ^ ((r & 7) << 4));
            *(uint4*)((char*)Wsh + off) = v;
        }
        // ---- stage X K-half: 64 rows x 128 k
        #pragma unroll
        for (int p = 0; p < 4; ++p) {
            const int j  = t + p * 256;          // 1024 chunks of 8
            const int r  = j >> 4, k8 = j & 15;
            const float* gp = &X[(size_t)(row0 + r) * KK + ph * 128 + k8 * 8];
            const float4 a = *(const float4*)(gp);
            const float4 bq = *(const float4*)(gp + 4);
            uint4 v;
            v.x = (unsigned)f2b(a.x)  | ((unsigned)f2b(a.y)  << 16);
            v.y = (unsigned)f2b(a.z)  | ((unsigned)f2b(a.w)  << 16);
            v.z = (unsigned)f2b(bq.x) | ((unsigned)f2b(bq.y) << 16);
            v.w = (unsigned)f2b(bq.z) | ((unsigned)f2b(bq.w) << 16);
            const int off = r * 256 + ((k8 * 16) ^ ((r & 7) << 4));
            *(uint4*)((char*)Xsh + off) = v;
        }
        __syncthreads();

        // ---- MFMA: 4 k-steps of 32 within this K-half
        #pragma unroll
        for (int kk = 0; kk < 4; ++kk) {
            const int kb = kk * 64 + ((lane >> 4) << 4);   // byte col in half
            bf16x8 af[2], bfr[4];
            #pragma unroll
            for (int m = 0; m < 2; ++m) {
                const int r = 32 * wm + 16 * m + (lane & 15);
                af[m] = *(const bf16x8*)((const char*)Xsh + r * 256 + (kb ^ ((r & 7) << 4)));
            }
            #pragma unroll
            for (int n = 0; n < 4; ++n) {
                const int d = 64 * wn + 16 * n + (lane & 15);
                bfr[n] = *(const bf16x8*)((const char*)Wsh + d * 256 + (kb ^ ((d & 7) << 4)));
            }
            #pragma unroll
            for (int m = 0; m < 2; ++m)
                #pragma unroll
                for (int n = 0; n < 4; ++n)
                    acc[m][n] = __builtin_amdgcn_mfma_f32_16x16x32_bf16(af[m], bfr[n], acc[m][n], 0, 0, 0);
        }
        __syncthreads();
    }

    // ---- bias add, bf16 store, per-col partial sums
    // C/D layout: col = lane&15, row = (lane>>4)*4 + j   [HW-verified]
    const int csub = (lane & 15);
    float bv[4];
    #pragma unroll
    for (int n = 0; n < 4; ++n) bv[n] = bvec[64 * wn + 16 * n + csub];

    float s[4] = {0.f, 0.f, 0.f, 0.f}, q[4] = {0.f, 0.f, 0.f, 0.f};
    #pragma unroll
    for (int m = 0; m < 2; ++m) {
        #pragma unroll
        for (int j = 0; j < 4; ++j) {
            const int row = row0 + 32 * wm + 16 * m + ((lane >> 4) << 2) + j;
            #pragma unroll
            for (int n = 0; n < 4; ++n) {
                const float v = acc[m][n][j] + bv[n];
                H[(size_t)row * DD + 64 * wn + 16 * n + csub] = f2b(v);
                s[n] += v;
                q[n] += v * v;
            }
        }
    }
    // reduce across the 4 lane-groups (rows) -> lanes with same lane&15
    #pragma unroll
    for (int n = 0; n < 4; ++n) {
        s[n] += __shfl_xor(s[n], 16); s[n] += __shfl_xor(s[n], 32);
        q[n] += __shfl_xor(q[n], 16); q[n] += __shfl_xor(q[n], 32);
    }
    float* red = (float*)Xsh;   // 512 floats, safe after final barrier above
    if (lane < 16) {
        #pragma unroll
        for (int n = 0; n < 4; ++n) {
            red[w * 64 + n * 16 + lane]       = s[n];
            red[256 + w * 64 + n * 16 + lane] = q[n];
        }
    }
    __syncthreads();
    if (t < 128) {
        const int c = t, i = c & 63, vn = c >> 6;   // waves {vn, vn+2} own col c
        const float S = red[vn * 64 + i] + red[(2 + vn) * 64 + i];
        const float Q = red[256 + vn * 64 + i] + red[256 + (2 + vn) * 64 + i];
        atomicAdd(&sums[src * 256 + c], S);
        atomicAdd(&sums[src * 256 + 128 + c], Q);
    }
}

// ---------------------------------------------------------------------------
// Kernel B: finalize stats -> scale/shift per source
// ---------------------------------------------------------------------------
__global__ void k_stats(const float* __restrict__ sums,
                        const float* __restrict__ gamma,
                        const float* __restrict__ beta,
                        float* __restrict__ ss)   // [2][2][D]: scale, shift
{
    const int t = threadIdx.x;
    if (t < 256) {
        const int src = t >> 7;
        const int d   = t & 127;
        const float invn = 1.0f / (float)NROWS;
        const float mean = sums[src * 256 + d] * invn;
        const float var  = sums[src * 256 + 128 + d] * invn - mean * mean;
        const float sc   = gamma[d] / sqrtf(var + EPS);
        const float sh   = beta[d] - mean * sc;
        ss[src * 256 + d]       = sc;
        ss[src * 256 + 128 + d] = sh;
    }
}

// ---------------------------------------------------------------------------
// Kernel C: normalize + leaky, windowed sim, masked softmax, weighted blend
// grid: 16*128 = 2048 blocks (32 n-positions each), 256 threads
// ---------------------------------------------------------------------------
__global__ __launch_bounds__(256) void k_attn(
    const float* __restrict__ x,
    const float* __restrict__ xt,
    const unsigned short* __restrict__ h,   // [2][NROWS][D] bf16
    const float* __restrict__ ss,           // [2][2][D]
    float* __restrict__ out,                // [B*N*K]
    float* __restrict__ feat)               // [B*N*7]
{
    const int blk  = blockIdx.x;
    const int bb   = blk >> 7;
    const int tile = blk & 127;
    const int n0   = tile * 32;
    const int t    = threadIdx.x;

    __shared__ float ex[32][132];
    __shared__ float et[38][132];
    __shared__ float attn[32][8];

    const unsigned short* __restrict__ Hx = h;
    const unsigned short* __restrict__ Ht = h + (size_t)NROWS * DD;
    const size_t rowbase = (size_t)bb * NN;

    // emb_x: 32 rows x 16 chunks of 8 bf16, normalize + leaky on the fly
    #pragma unroll
    for (int p = 0; p < 2; ++p) {
        const int j = t + p * 256;             // 512 chunks
        const int r = j >> 4, c8 = j & 15;
        const uint4 u = *(const uint4*)(&Hx[(rowbase + n0 + r) * DD + c8 * 8]);
        const float4 sca = *(const float4*)(&ss[c8 * 8]);
        const float4 scb = *(const float4*)(&ss[c8 * 8 + 4]);
        const float4 sha = *(const float4*)(&ss[128 + c8 * 8]);
        const float4 shb = *(const float4*)(&ss[128 + c8 * 8 + 4]);
        float* dst = &ex[r][c8 * 8];
        dst[0] = lrelu(b2f_lo(u.x) * sca.x + sha.x);
        dst[1] = lrelu(b2f_hi(u.x) * sca.y + sha.y);
        dst[2] = lrelu(b2f_lo(u.y) * sca.z + sha.z);
        dst[3] = lrelu(b2f_hi(u.y) * sca.w + sha.w);
        dst[4] = lrelu(b2f_lo(u.z) * scb.x + shb.x);
        dst[5] = lrelu(b2f_hi(u.z) * scb.y + shb.y);
        dst[6] = lrelu(b2f_lo(u.w) * scb.z + shb.z);
        dst[7] = lrelu(b2f_hi(u.w) * scb.w + shb.w);
    }
    // emb_t: 38 rows (clamped window) x 16 chunks
    #pragma unroll
    for (int p = 0; p < 3; ++p) {
        const int j = t + p * 256;             // 608 chunks
        if (j < 608) {
            const int r = j >> 4, c8 = j & 15;
            int g = n0 - HWIN + r;
            g = min(max(g, 0), NN - 1);
            const uint4 u = *(const uint4*)(&Ht[(rowbase + g) * DD + c8 * 8]);
            const float4 sca = *(const float4*)(&ss[256 + c8 * 8]);
            const float4 scb = *(const float4*)(&ss[256 + c8 * 8 + 4]);
            const float4 sha = *(const float4*)(&ss[384 + c8 * 8]);
            const float4 shb = *(const float4*)(&ss[384 + c8 * 8 + 4]);
            float* dst = &et[r][c8 * 8];
            dst[0] = lrelu(b2f_lo(u.x) * sca.x + sha.x);
            dst[1] = lrelu(b2f_hi(u.x) * sca.y + sha.y);
            dst[2] = lrelu(b2f_lo(u.y) * sca.z + sha.z);
            dst[3] = lrelu(b2f_hi(u.y) * sca.w + sha.w);
            dst[4] = lrelu(b2f_lo(u.z) * scb.x + shb.x);
            dst[5] = lrelu(b2f_hi(u.z) * scb.y + shb.y);
            dst[6] = lrelu(b2f_lo(u.w) * scb.z + shb.z);
            dst[7] = lrelu(b2f_hi(u.w) * scb.w + shb.w);
        }
    }
    __syncthreads();

    // sim: 32 n x 7 w = 224 dots of length 128
    if (t < 224) {
        const int n_i = t / 7;
        const int wv  = t % 7;
        const float* a = &ex[n_i][0];
        const float* b = &et[n_i + wv][0];
        float acc = 0.f;
        #pragma unroll
        for (int d4 = 0; d4 < 128; d4 += 4) {
            const float4 av = *(const float4*)(a + d4);
            const float4 bv = *(const float4*)(b + d4);
            acc += av.x * bv.x + av.y * bv.y + av.z * bv.z + av.w * bv.w;
        }
        feat[(rowbase + n0 + n_i) * WIN + wv] = acc;   // feat_fused = raw sim
        attn[n_i][wv] = acc;
    }
    __syncthreads();

    // masked softmax over the window, per n
    if (t < 32) {
        const int n = n0 + t;
        float mx = -1e30f;
        #pragma unroll
        for (int wv = 0; wv < WIN; ++wv) {
            const int c = n + wv - HWIN;
            if (c >= 0 && c < NN) mx = fmaxf(mx, attn[t][wv]);
        }
        float e[WIN];
        float esum = 0.f;
        #pragma unroll
        for (int wv = 0; wv < WIN; ++wv) {
            const int c = n + wv - HWIN;
            const bool valid = (c >= 0 && c < NN);
            e[wv] = valid ? expf(attn[t][wv] - mx) : 0.f;
            esum += e[wv];
        }
        const float inv = 1.0f / esum;
        #pragma unroll
        for (int wv = 0; wv < WIN; ++wv) attn[t][wv] = e[wv] * inv;
    }
    __syncthreads();

    // out = alpha*x + (1-alpha) * sum_w attn[w] * xt[clamped window row]
    #pragma unroll
    for (int p = 0; p < 8; ++p) {
        const int idx = t + p * 256;            // 2048 float4 = 32 rows x 64
        const int n_i = idx >> 6, e4 = idx & 63;
        const int n = n0 + n_i;
        const float4 xv = *(const float4*)(&x[(rowbase + n) * KK + e4 * 4]);
        float4 acc = make_float4(0.f, 0.f, 0.f, 0.f);
        #pragma unroll
        for (int wv = 0; wv < WIN; ++wv) {
            int g = n + wv - HWIN;
            g = min(max(g, 0), NN - 1);
            const float aw = attn[n_i][wv];
            const float4 tv = *(const float4*)(&xt[(rowbase + g) * KK + e4 * 4]);
            acc.x += aw * tv.x;
            acc.y += aw * tv.y;
            acc.z += aw * tv.z;
            acc.w += aw * tv.w;
        }
        float4 o;
        o.x = ALPHA * xv.x + (1.f - ALPHA) * acc.x;
        o.y = ALPHA * xv.y + (1.f - ALPHA) * acc.y;
        o.z = ALPHA * xv.z + (1.f - ALPHA) * acc.z;
        o.w = ALPHA * xv.w + (1.f - ALPHA) * acc.w;
        *(float4*)(&out[(rowbase + n) * KK + e4 * 4]) = o;
    }
}

// ---------------------------------------------------------------------------
extern "C" void kernel_launch(void* const* d_in, const int* in_sizes, int n_in,
                              void* d_out, int out_size, void* d_ws, size_t ws_size,
                              hipStream_t stream) {
    const float* x     = (const float*)d_in[0];
    const float* xt    = (const float*)d_in[1];
    const float* W     = (const float*)d_in[2];
    const float* bvec  = (const float*)d_in[3];
    const float* gamma = (const float*)d_in[4];
    const float* beta  = (const float*)d_in[5];

    float* out  = (float*)d_out;
    float* feat = out + (size_t)BB * NN * KK;

    char*  ws   = (char*)d_ws;
    unsigned short* h = (unsigned short*)ws;                // 2 x 65536 x 128 bf16 = 32 MiB
    float* sums = (float*)(ws + (size_t)33554432);          // 512 f32
    float* ss   = (float*)(ws + (size_t)33556480);          // 512 f32

    hipMemsetAsync(sums, 0, 512 * sizeof(float), stream);
    k_embed_mfma<<<2048, 256, 0, stream>>>(x, xt, W, bvec, h, sums);
    k_stats<<<1, 256, 0, stream>>>(sums, gamma, beta, ss);
    k_attn<<<2048, 256, 0, stream>>>(x, xt, h, ss, out, feat);
}

// Round 3
// 221.002 us; speedup vs baseline: 3.0460x; 1.0746x over previous
//
#include <hip/hip_runtime.h>
#include <math.h>

#define BB 16
#define NN 4096
#define DD 128
#define KK 256          // C*P = 4*64
#define NROWS (BB*NN)   // 65536
#define WIN 7
#define HWIN 3
#define ALPHA 0.5f
#define EPS 1e-5f

typedef __attribute__((ext_vector_type(8))) short bf16x8;
typedef __attribute__((ext_vector_type(4))) float f32x4;

__device__ __forceinline__ unsigned short f2b(float f) {     // f32 -> bf16 RNE
    unsigned u = __float_as_uint(f);
    u += 0x7FFFu + ((u >> 16) & 1u);
    return (unsigned short)(u >> 16);
}
__device__ __forceinline__ float b2f_lo(unsigned v) { return __uint_as_float(v << 16); }
__device__ __forceinline__ float b2f_hi(unsigned v) { return __uint_as_float(v & 0xFFFF0000u); }
__device__ __forceinline__ float lrelu(float v) { return v >= 0.f ? v : 0.1f * v; }

__device__ __forceinline__ uint4 pack8(float4 a, float4 b) {
    uint4 v;
    v.x = (unsigned)f2b(a.x)  | ((unsigned)f2b(a.y)  << 16);
    v.y = (unsigned)f2b(a.z)  | ((unsigned)f2b(a.w)  << 16);
    v.z = (unsigned)f2b(b.x)  | ((unsigned)f2b(b.y)  << 16);
    v.w = (unsigned)f2b(b.z)  | ((unsigned)f2b(b.w)  << 16);
    return v;
}

// ---------------------------------------------------------------------------
// Kernel P: W f32 [128][256] -> bf16, PRE-SWIZZLED global image of the LDS
// layout used by k_embed (row stride 512 B, 16B chunk XOR (row&7)<<4).
// ---------------------------------------------------------------------------
__global__ __launch_bounds__(256) void k_prep(
    const float* __restrict__ W, unsigned char* __restrict__ Wswz)
{
    const int id = blockIdx.x * 256 + threadIdx.x;   // 0..4095
    const int d  = id >> 5, c8 = id & 31;
    const float4 a = *(const float4*)(&W[(size_t)d * KK + c8 * 8]);
    const float4 b = *(const float4*)(&W[(size_t)d * KK + c8 * 8 + 4]);
    const int off = d * 512 + ((c8 * 16) ^ ((d & 7) << 4));
    *(uint4*)(Wswz + off) = pack8(a, b);
}

// ---------------------------------------------------------------------------
// Kernel A: h = bf16mfma(X @ W^T) + b, h stored bf16, + per-feature sum/sumsq.
// grid: 256 blocks x 512 threads. Block = 512 rows. W in LDS once (64 KB),
// B-frags hoisted to registers, X double-buffered 64-row subtiles (2x32 KB).
// ---------------------------------------------------------------------------
__device__ __forceinline__ void stage_x(const float* __restrict__ X, int grow0,
                                        unsigned short* dst, int t)
{
    #pragma unroll
    for (int p = 0; p < 4; ++p) {
        const int j  = t + p * 512;          // 0..2047 chunks of 8
        const int r  = j >> 5, c8 = j & 31;
        const float* gp = X + (size_t)(grow0 + r) * KK + c8 * 8;
        const float4 a = *(const float4*)(gp);
        const float4 b = *(const float4*)(gp + 4);
        const int off = r * 512 + ((c8 * 16) ^ ((r & 7) << 4));
        *(uint4*)((char*)dst + off) = pack8(a, b);
    }
}

__global__ __launch_bounds__(512) void k_embed(
    const float* __restrict__ x,
    const float* __restrict__ xt,
    const uint4* __restrict__ Wswz,       // 64 KB pre-swizzled bf16 image
    const float* __restrict__ bvec,
    unsigned short* __restrict__ h_out,   // [2][NROWS][DD] bf16
    float* __restrict__ sums)             // [2][2][DD]
{
    __shared__ unsigned short Wsh[128 * 256];     // 64 KB
    __shared__ unsigned short Xs[2][64 * 256];    // 2 x 32 KB

    const int blk  = blockIdx.x;          // 256
    const int src  = blk >> 7;
    const int tile = blk & 127;
    const int row0 = tile * 512;
    const float* __restrict__ X = src ? xt : x;
    unsigned short* __restrict__ H = h_out + (size_t)src * NROWS * DD;

    const int t    = threadIdx.x;
    const int lane = t & 63;
    const int w    = t >> 6;              // 0..7
    const int wm   = w & 1;               // row half (32 rows)
    const int wn   = w >> 1;              // col quarter (32 cols)
    const int l15  = lane & 15;
    const int lg   = lane >> 4;           // 0..3

    // W image -> LDS, linear copy (already swizzled)
    {
        uint4* d4 = (uint4*)Wsh;
        #pragma unroll
        for (int p = 0; p < 8; ++p) d4[t + p * 512] = Wswz[t + p * 512];
    }
    stage_x(X, row0, &Xs[0][0], t);
    __syncthreads();

    // B-fragments once: breg[n][k] for this wave's 32 cols
    bf16x8 breg[2][8];
    #pragma unroll
    for (int n = 0; n < 2; ++n) {
        const int d = 32 * wn + 16 * n + l15;
        #pragma unroll
        for (int k = 0; k < 8; ++k) {
            const int addr = d * 512 + (((k * 64) + lg * 16) ^ ((d & 7) << 4));
            breg[n][k] = *(const bf16x8*)((const char*)Wsh + addr);
        }
    }

    const float bv0 = bvec[32 * wn + l15];
    const float bv1 = bvec[32 * wn + 16 + l15];
    float s0 = 0.f, s1 = 0.f, q0 = 0.f, q1 = 0.f;

    for (int st = 0; st < 8; ++st) {
        const int cur = st & 1;
        f32x4 acc[2][2];
        #pragma unroll
        for (int m = 0; m < 2; ++m)
            #pragma unroll
            for (int n = 0; n < 2; ++n)
                #pragma unroll
                for (int j = 0; j < 4; ++j) acc[m][n][j] = 0.f;

        const char* xb = (const char*)&Xs[cur][0];
        #pragma unroll
        for (int k = 0; k < 8; ++k) {
            bf16x8 af[2];
            #pragma unroll
            for (int m = 0; m < 2; ++m) {
                const int r = 32 * wm + 16 * m + l15;
                const int addr = r * 512 + (((k * 64) + lg * 16) ^ ((r & 7) << 4));
                af[m] = *(const bf16x8*)(xb + addr);
            }
            acc[0][0] = __builtin_amdgcn_mfma_f32_16x16x32_bf16(af[0], breg[0][k], acc[0][0], 0, 0, 0);
            acc[0][1] = __builtin_amdgcn_mfma_f32_16x16x32_bf16(af[0], breg[1][k], acc[0][1], 0, 0, 0);
            acc[1][0] = __builtin_amdgcn_mfma_f32_16x16x32_bf16(af[1], breg[0][k], acc[1][0], 0, 0, 0);
            acc[1][1] = __builtin_amdgcn_mfma_f32_16x16x32_bf16(af[1], breg[1][k], acc[1][1], 0, 0, 0);
        }

        if (st < 7) stage_x(X, row0 + (st + 1) * 64, &Xs[cur ^ 1][0], t);

        // epilogue: bias, bf16 store, sums.  C/D: col=lane&15, row=lg*4+j
        #pragma unroll
        for (int m = 0; m < 2; ++m) {
            #pragma unroll
            for (int j = 0; j < 4; ++j) {
                const int row = row0 + st * 64 + 32 * wm + 16 * m + lg * 4 + j;
                const float v0 = acc[m][0][j] + bv0;
                const float v1 = acc[m][1][j] + bv1;
                H[(size_t)row * DD + 32 * wn + l15]      = f2b(v0);
                H[(size_t)row * DD + 32 * wn + 16 + l15] = f2b(v1);
                s0 += v0; q0 += v0 * v0;
                s1 += v1; q1 += v1 * v1;
            }
        }
        __syncthreads();
    }

    // reduce sums: intra-wave over lane groups, cross-wave (wm pair) via LDS
    s0 += __shfl_xor(s0, 16); s0 += __shfl_xor(s0, 32);
    s1 += __shfl_xor(s1, 16); s1 += __shfl_xor(s1, 32);
    q0 += __shfl_xor(q0, 16); q0 += __shfl_xor(q0, 32);
    q1 += __shfl_xor(q1, 16); q1 += __shfl_xor(q1, 32);
    float* red = (float*)Wsh;     // [w][n][16] sums, +256 sumsq
    if (lane < 16) {
        red[(w * 2 + 0) * 16 + l15]       = s0;
        red[(w * 2 + 1) * 16 + l15]       = s1;
        red[256 + (w * 2 + 0) * 16 + l15] = q0;
        red[256 + (w * 2 + 1) * 16 + l15] = q1;
    }
    __syncthreads();
    if (t < 128) {
        const int wn_ = t >> 5, n_ = (t >> 4) & 1, li = t & 15;
        float S = 0.f, Q = 0.f;
        #pragma unroll
        for (int wm_ = 0; wm_ < 2; ++wm_) {
            const int w_ = wn_ * 2 + wm_;
            S += red[(w_ * 2 + n_) * 16 + li];
            Q += red[256 + (w_ * 2 + n_) * 16 + li];
        }
        atomicAdd(&sums[src * 256 + t], S);
        atomicAdd(&sums[src * 256 + 128 + t], Q);
    }
}

// ---------------------------------------------------------------------------
// Kernel B: finalize stats -> scale/shift per source
// ---------------------------------------------------------------------------
__global__ void k_stats(const float* __restrict__ sums,
                        const float* __restrict__ gamma,
                        const float* __restrict__ beta,
                        float* __restrict__ ss)
{
    const int t = threadIdx.x;
    if (t < 256) {
        const int src = t >> 7;
        const int d   = t & 127;
        const float invn = 1.0f / (float)NROWS;
        const float mean = sums[src * 256 + d] * invn;
        const float var  = sums[src * 256 + 128 + d] * invn - mean * mean;
        const float sc   = gamma[d] / sqrtf(var + EPS);
        const float sh   = beta[d] - mean * sc;
        ss[src * 256 + d]       = sc;
        ss[src * 256 + 128 + d] = sh;
    }
}

// ---------------------------------------------------------------------------
// Kernel C: normalize + leaky, windowed sim, masked softmax, weighted blend.
// xt window staged to LDS (bf16) for the output phase; softmax overlapped.
// ---------------------------------------------------------------------------
__global__ __launch_bounds__(256) void k_attn(
    const float* __restrict__ x,
    const float* __restrict__ xt,
    const unsigned short* __restrict__ h,   // [2][NROWS][DD] bf16
    const float* __restrict__ ss,
    float* __restrict__ out,
    float* __restrict__ feat)
{
    const int blk  = blockIdx.x;
    const int bb   = blk >> 7;
    const int tile = blk & 127;
    const int n0   = tile * 32;
    const int t    = threadIdx.x;

    __shared__ float ex[32][132];
    __shared__ float et[38][132];           // later overlaid with xt window (bf16)
    __shared__ float attnw[32][8];

    const unsigned short* __restrict__ Hx = h;
    const unsigned short* __restrict__ Ht = h + (size_t)NROWS * DD;
    const size_t rowbase = (size_t)bb * NN;

    // phase 1: emb_x / emb_t -> LDS f32 (normalize + leaky on the fly)
    #pragma unroll
    for (int p = 0; p < 2; ++p) {
        const int j = t + p * 256;
        const int r = j >> 4, c8 = j & 15;
        const uint4 u = *(const uint4*)(&Hx[(rowbase + n0 + r) * DD + c8 * 8]);
        const float4 sca = *(const float4*)(&ss[c8 * 8]);
        const float4 scb = *(const float4*)(&ss[c8 * 8 + 4]);
        const float4 sha = *(const float4*)(&ss[128 + c8 * 8]);
        const float4 shb = *(const float4*)(&ss[128 + c8 * 8 + 4]);
        float* dst = &ex[r][c8 * 8];
        dst[0] = lrelu(b2f_lo(u.x) * sca.x + sha.x);
        dst[1] = lrelu(b2f_hi(u.x) * sca.y + sha.y);
        dst[2] = lrelu(b2f_lo(u.y) * sca.z + sha.z);
        dst[3] = lrelu(b2f_hi(u.y) * sca.w + sha.w);
        dst[4] = lrelu(b2f_lo(u.z) * scb.x + shb.x);
        dst[5] = lrelu(b2f_hi(u.z) * scb.y + shb.y);
        dst[6] = lrelu(b2f_lo(u.w) * scb.z + shb.z);
        dst[7] = lrelu(b2f_hi(u.w) * scb.w + shb.w);
    }
    #pragma unroll
    for (int p = 0; p < 3; ++p) {
        const int j = t + p * 256;
        if (j < 608) {
            const int r = j >> 4, c8 = j & 15;
            int g = n0 - HWIN + r;
            g = min(max(g, 0), NN - 1);
            const uint4 u = *(const uint4*)(&Ht[(rowbase + g) * DD + c8 * 8]);
            const float4 sca = *(const float4*)(&ss[256 + c8 * 8]);
            const float4 scb = *(const float4*)(&ss[256 + c8 * 8 + 4]);
            const float4 sha = *(const float4*)(&ss[384 + c8 * 8]);
            const float4 shb = *(const float4*)(&ss[384 + c8 * 8 + 4]);
            float* dst = &et[r][c8 * 8];
            dst[0] = lrelu(b2f_lo(u.x) * sca.x + sha.x);
            dst[1] = lrelu(b2f_hi(u.x) * sca.y + sha.y);
            dst[2] = lrelu(b2f_lo(u.y) * sca.z + sha.z);
            dst[3] = lrelu(b2f_hi(u.y) * sca.w + sha.w);
            dst[4] = lrelu(b2f_lo(u.z) * scb.x + shb.x);
            dst[5] = lrelu(b2f_hi(u.z) * scb.y + shb.y);
            dst[6] = lrelu(b2f_lo(u.w) * scb.z + shb.z);
            dst[7] = lrelu(b2f_hi(u.w) * scb.w + shb.w);
        }
    }
    __syncthreads();

    // phase 2: sim (224 threads: 32 n x 7 w dots of length 128)
    if (t < 224) {
        const int n_i = t / 7;
        const int wv  = t % 7;
        const float* a = &ex[n_i][0];
        const float* b = &et[n_i + wv][0];
        float acc = 0.f;
        #pragma unroll
        for (int d4 = 0; d4 < 128; d4 += 4) {
            const float4 av = *(const float4*)(a + d4);
            const float4 bv = *(const float4*)(b + d4);
            acc += av.x * bv.x + av.y * bv.y + av.z * bv.z + av.w * bv.w;
        }
        feat[(rowbase + n0 + n_i) * WIN + wv] = acc;
        attnw[n_i][wv] = acc;
    }
    __syncthreads();

    // phase 3: xt window -> LDS bf16 (threads <224) || softmax (threads >=224)
    unsigned short* xts = (unsigned short*)&et[0][0];   // [38][256] bf16, 19456 B
    if (t < 224) {
        #pragma unroll
        for (int p = 0; p < 6; ++p) {
            const int j = t + p * 224;       // 0..1215 chunks of 8
            if (j < 1216) {
                const int r = j >> 5, c8 = j & 31;
                int g = n0 - HWIN + r;
                g = min(max(g, 0), NN - 1);
                const float* gp = &xt[(rowbase + g) * KK + c8 * 8];
                const float4 a = *(const float4*)(gp);
                const float4 b = *(const float4*)(gp + 4);
                *(uint4*)((char*)xts + r * 512 + c8 * 16) = pack8(a, b);
            }
        }
    } else {
        const int n_i = t - 224;
        const int n = n0 + n_i;
        float mx = -1e30f;
        #pragma unroll
        for (int wv = 0; wv < WIN; ++wv) {
            const int c = n + wv - HWIN;
            if (c >= 0 && c < NN) mx = fmaxf(mx, attnw[n_i][wv]);
        }
        float e[WIN];
        float esum = 0.f;
        #pragma unroll
        for (int wv = 0; wv < WIN; ++wv) {
            const int c = n + wv - HWIN;
            const bool valid = (c >= 0 && c < NN);
            e[wv] = valid ? expf(attnw[n_i][wv] - mx) : 0.f;
            esum += e[wv];
        }
        const float inv = 1.0f / esum;
        #pragma unroll
        for (int wv = 0; wv < WIN; ++wv) attnw[n_i][wv] = e[wv] * inv;
    }
    __syncthreads();

    // phase 4: out = alpha*x + (1-alpha) * sum_w attn[w] * xt_window (LDS)
    #pragma unroll
    for (int p = 0; p < 8; ++p) {
        const int idx = t + p * 256;            // 2048 float4-chunks
        const int n_i = idx >> 6, e4 = idx & 63;
        const int n = n0 + n_i;
        const float4 xv = *(const float4*)(&x[(rowbase + n) * KK + e4 * 4]);
        float4 acc = make_float4(0.f, 0.f, 0.f, 0.f);
        #pragma unroll
        for (int wv = 0; wv < WIN; ++wv) {
            const float aw = attnw[n_i][wv];
            const uint2 u = *(const uint2*)((const char*)xts + (n_i + wv) * 512 + e4 * 8);
            acc.x += aw * b2f_lo(u.x);
            acc.y += aw * b2f_hi(u.x);
            acc.z += aw * b2f_lo(u.y);
            acc.w += aw * b2f_hi(u.y);
        }
        float4 o;
        o.x = ALPHA * xv.x + (1.f - ALPHA) * acc.x;
        o.y = ALPHA * xv.y + (1.f - ALPHA) * acc.y;
        o.z = ALPHA * xv.z + (1.f - ALPHA) * acc.z;
        o.w = ALPHA * xv.w + (1.f - ALPHA) * acc.w;
        *(float4*)(&out[(rowbase + n) * KK + e4 * 4]) = o;
    }
}

// ---------------------------------------------------------------------------
extern "C" void kernel_launch(void* const* d_in, const int* in_sizes, int n_in,
                              void* d_out, int out_size, void* d_ws, size_t ws_size,
                              hipStream_t stream) {
    const float* x     = (const float*)d_in[0];
    const float* xt    = (const float*)d_in[1];
    const float* W     = (const float*)d_in[2];
    const float* bvec  = (const float*)d_in[3];
    const float* gamma = (const float*)d_in[4];
    const float* beta  = (const float*)d_in[5];

    float* out  = (float*)d_out;
    float* feat = out + (size_t)BB * NN * KK;

    char* ws = (char*)d_ws;
    unsigned short* h  = (unsigned short*)ws;                  // 32 MiB
    float* sums        = (float*)(ws + 33554432);              // 2 KiB
    float* ss          = (float*)(ws + 33556480);              // 2 KiB
    unsigned char* Wsz = (unsigned char*)(ws + 33558528);      // 64 KiB

    hipMemsetAsync(sums, 0, 512 * sizeof(float), stream);
    k_prep<<<16, 256, 0, stream>>>(W, Wsz);
    k_embed<<<256, 512, 0, stream>>>(x, xt, (const uint4*)Wsz, bvec, h, sums);
    k_stats<<<1, 256, 0, stream>>>(sums, gamma, beta, ss);
    k_attn<<<2048, 256, 0, stream>>>(x, xt, h, ss, out, feat);
}